// Round 18
// baseline (152.565 us; speedup 1.0000x reference)
//
#include <hip/hip_runtime.h>
#include <hip/hip_bf16.h>
#include <hip/hip_fp8.h>
#include <math.h>

#define EMB 64
#define HEADS 4
#define HC 256
#define EDGE_DIM 16
#define NEG_SLOPE 0.2f
#define LN_EPS 1e-5f
#define NCOLS 272   // 256 xw cols + 4 a_src + 4 a_dst + 8 pad
#define CAP 512     // records staged in LDS per chunk
#define NPB 16      // nodes per block (2 per wave, 8 waves)

typedef __attribute__((ext_vector_type(8))) short short8;
typedef __attribute__((ext_vector_type(4))) float f32x4;
typedef __attribute__((ext_vector_type(2))) float f32x2;

__device__ __forceinline__ float bflo(unsigned int u) { return __uint_as_float(u << 16); }
__device__ __forceinline__ float bfhi(unsigned int u) { return __uint_as_float(u & 0xffff0000u); }
__device__ __forceinline__ unsigned short bfb(float f) {
    __hip_bfloat16 h = __float2bfloat16(f);
    return *(unsigned short*)&h;
}
__device__ __forceinline__ unsigned int pack_bf2(float a, float b) {
    return (unsigned int)bfb(a) | ((unsigned int)bfb(b) << 16);
}
__device__ __forceinline__ unsigned char ftofp8(float f) {
    __hip_fp8_e4m3 t(f); return (unsigned char)t.__x;
}

// prep: zero cnt; we_att; WpT[64][256] bf16 (transposed Wp); WxT[272][64] bf16
__global__ void k_prep(const float* __restrict__ W_edge, const float* __restrict__ att_edge,
                       float* __restrict__ we_att, const float* __restrict__ Wp,
                       unsigned short* __restrict__ WpT, const float* __restrict__ W,
                       const float* __restrict__ att_src, const float* __restrict__ att_dst,
                       unsigned short* __restrict__ WxT, int* __restrict__ cnt, int n) {
    int i = blockIdx.x * blockDim.x + threadIdx.x;
    if (i < n) cnt[i] = 0;
    if (i < EDGE_DIM * HEADS) {
        int d = i >> 2, h = i & 3;
        float acc = 0.0f;
#pragma unroll
        for (int c = 0; c < EMB; ++c)
            acc += W_edge[d * HC + h * EMB + c] * att_edge[h * EMB + c];
        we_att[d * HEADS + h] = acc;
    }
    if (i < HC * EMB) {
        int k = i >> 8, jj = i & 255;              // WpT[k][jj] = Wp[jj][k]
        WpT[i] = bfb(Wp[jj * EMB + k]);
    }
    if (i < NCOLS * EMB) {
        int c = i >> 6, k = i & 63;
        float v = 0.0f;
        if (c < HC) {
            v = W[k * HC + c];
        } else if (c < HC + 4) {
            int h = c - HC;
            float s = 0.0f;
#pragma unroll
            for (int j = 0; j < EMB; ++j) s += W[k * HC + h * EMB + j] * att_src[h * EMB + j];
            v = s;
        } else if (c < HC + 8) {
            int h = c - HC - 4;
            float s = 0.0f;
#pragma unroll
            for (int j = 0; j < EMB; ++j) s += W[k * HC + h * EMB + j] * att_dst[h * EMB + j];
            v = s;
        }
        WxT[i] = bfb(v);
    }
}

// ---- MFMA GEMM: [xw(fp8) | a_src | a_dst] = x @ Wx ; 16 nodes/block, 4 waves ----
// fused tail: rank atomic + edge-attn projection ae = edge_attr . we_att (bf16x4)
__global__ void __launch_bounds__(256)
k_xw_mfma(const float* __restrict__ x, const unsigned short* __restrict__ WxT,
          unsigned char* __restrict__ xwf8, float* __restrict__ a_src,
          float* __restrict__ a_dst, int n,
          const int* __restrict__ ei, const float* __restrict__ edge_attr,
          const float* __restrict__ we_att, int* __restrict__ cnt,
          int* __restrict__ rank, uint2* __restrict__ aeb, int E) {
    int tid = threadIdx.x, lane = tid & 63, wv = tid >> 6;
    int g = lane >> 4, r16 = lane & 15;
    __shared__ float wa[EDGE_DIM * HEADS];
    if (tid < EDGE_DIM * HEADS) wa[tid] = we_att[tid];
    __syncthreads();

    int mbase = blockIdx.x * 16;
    int row = mbase + r16;
    if (row >= n) row = n - 1;

    const float* xr = x + (size_t)row * EMB;
    short8 A[2];
#pragma unroll
    for (int kk = 0; kk < 2; ++kk) {
        float4 f0 = *(const float4*)(xr + kk * 32 + 8 * g);
        float4 f1 = *(const float4*)(xr + kk * 32 + 8 * g + 4);
        short8 a;
        a[0] = (short)bfb(f0.x); a[1] = (short)bfb(f0.y);
        a[2] = (short)bfb(f0.z); a[3] = (short)bfb(f0.w);
        a[4] = (short)bfb(f1.x); a[5] = (short)bfb(f1.y);
        a[6] = (short)bfb(f1.z); a[7] = (short)bfb(f1.w);
        A[kk] = a;
    }

    for (int t = wv; t <= 16; t += 4) {
        int col = t * 16 + r16;
        const unsigned short* bp = WxT + (size_t)col * EMB + 8 * g;
        short8 B0 = *(const short8*)(bp);
        short8 B1 = *(const short8*)(bp + 32);
        f32x4 acc = {0.f, 0.f, 0.f, 0.f};
        acc = __builtin_amdgcn_mfma_f32_16x16x32_bf16(A[0], B0, acc, 0, 0, 0);
        acc = __builtin_amdgcn_mfma_f32_16x16x32_bf16(A[1], B1, acc, 0, 0, 0);
        if (t < 16) {
#pragma unroll
            for (int r = 0; r < 4; ++r) {
                int node = mbase + 4 * g + r;
                if (node < n) xwf8[(size_t)node * HC + col] = ftofp8(acc[r]);
            }
        } else {
#pragma unroll
            for (int r = 0; r < 4; ++r) {
                int node = mbase + 4 * g + r;
                if (node < n) {
                    if (r16 < 4) a_src[node * HEADS + r16] = acc[r];
                    else if (r16 < 8) a_dst[node * HEADS + r16 - 4] = acc[r];
                }
            }
        }
    }

    // fused tail: rank atomic + ae projection (hides edge_attr stream under atomics)
    int stride = gridDim.x * blockDim.x;
    for (int e = blockIdx.x * blockDim.x + tid; e < E; e += stride) {
        rank[e] = atomicAdd(&cnt[ei[E + e]], 1);
        const float4* ea4 = (const float4*)(edge_attr + (size_t)e * EDGE_DIM);
        float ae[HEADS] = {0.f, 0.f, 0.f, 0.f};
#pragma unroll
        for (int q = 0; q < 4; ++q) {
            float4 v4 = ea4[q];
            const float* vp = (const float*)&v4;
#pragma unroll
            for (int r = 0; r < 4; ++r) {
                float v = vp[r];
                int dd = q * 4 + r;
#pragma unroll
                for (int h = 0; h < HEADS; ++h) ae[h] += v * wa[dd * HEADS + h];
            }
        }
        uint2 ab;
        ab.x = pack_bf2(ae[0], ae[1]);
        ab.y = pack_bf2(ae[2], ae[3]);
        aeb[e] = ab;
    }
}

// ---------------- 3-dispatch exclusive scan over cnt[n] ----------------
__global__ void k_scan1(const int* __restrict__ cnt, int* __restrict__ tmp,
                        int* __restrict__ bsum, int n) {
    __shared__ int s[256];
    int i = blockIdx.x * 256 + threadIdx.x;
    int v = (i < n) ? cnt[i] : 0;
    s[threadIdx.x] = v;
    __syncthreads();
    for (int off = 1; off < 256; off <<= 1) {
        int t = (threadIdx.x >= off) ? s[threadIdx.x - off] : 0;
        __syncthreads();
        s[threadIdx.x] += t;
        __syncthreads();
    }
    if (i < n) tmp[i] = s[threadIdx.x];
    if (threadIdx.x == 255) bsum[blockIdx.x] = s[255];
}

__global__ void k_scan2(int* __restrict__ bsum, int nb) {
    __shared__ int s[256];
    int v = (threadIdx.x < nb) ? bsum[threadIdx.x] : 0;
    s[threadIdx.x] = v;
    __syncthreads();
    for (int off = 1; off < 256; off <<= 1) {
        int t = (threadIdx.x >= off) ? s[threadIdx.x - off] : 0;
        __syncthreads();
        s[threadIdx.x] += t;
        __syncthreads();
    }
    if (threadIdx.x < nb) bsum[threadIdx.x] = s[threadIdx.x] - v; // exclusive
}

__global__ void k_scan3(const int* __restrict__ tmp, const int* __restrict__ cnt,
                        const int* __restrict__ bsum, int* __restrict__ row_start, int n) {
    int i = blockIdx.x * 256 + threadIdx.x;
    if (i < n) row_start[i] = tmp[i] - cnt[i] + bsum[blockIdx.x];
}

// ---- scatter: alpha from precomputed ae (8B/edge); 16B CSR record write ----
// record = { ea01.bf16x2, ea23.bf16x2, src.u32, ae.int8x4 (scale 1/32) }
__global__ void k_scatter(const int* __restrict__ ei, const uint2* __restrict__ aeb,
                          const float* __restrict__ a_src, const float* __restrict__ a_dst,
                          const int* __restrict__ row_start, const int* __restrict__ rank,
                          uint4* __restrict__ recp, int E) {
    int e = blockIdx.x * blockDim.x + threadIdx.x;
    if (e >= E) return;
    int s = ei[e], d = ei[E + e];
    uint2 ab = aeb[e];
    float ae[HEADS];
    ae[0] = bflo(ab.x); ae[1] = bfhi(ab.x);
    ae[2] = bflo(ab.y); ae[3] = bfhi(ab.y);
    float4 as4 = *(const float4*)(a_src + (size_t)s * HEADS);
    float4 ad4 = *(const float4*)(a_dst + (size_t)d * HEADS);
    const float* asp = (const float*)&as4;
    const float* adp = (const float*)&ad4;
    float ea[HEADS];
    unsigned int aeq = 0;
#pragma unroll
    for (int h = 0; h < HEADS; ++h) {
        float al = asp[h] + adp[h] + ae[h];
        al = al >= 0.0f ? al : NEG_SLOPE * al;
        ea[h] = __expf(al);          // no max-subtraction needed: |al| < ~8
        int q = __float2int_rn(ae[h] * 32.0f);
        q = max(-127, min(127, q));
        aeq |= ((unsigned int)(q & 0xff)) << (8 * h);
    }
    int pos = row_start[d] + rank[e];
    uint4 w;
    w.x = pack_bf2(ea[0], ea[1]);
    w.y = pack_bf2(ea[2], ea[3]);
    w.z = (unsigned int)s;
    w.w = aeq;
    recp[pos] = w;
}

// two-phase gather batch: issue D independent row loads, then decode+accumulate
template<int D>
__device__ __forceinline__ void gather_batch(
    const uint4* recs, int o, int j, const unsigned char* xwf8, int lane,
    int h4, bool hodd, int sh1,
    float& acc0, float& acc1, float& acc2, float& acc3, float& dn, float& aeS) {
    int sv[D];
#pragma unroll
    for (int u = 0; u < D; ++u) sv[u] = (int)recs[o + j + u].z;
    unsigned int rv[D];
#pragma unroll
    for (int u = 0; u < D; ++u)
        rv[u] = *(const unsigned int*)(xwf8 + (size_t)sv[u] * HC + (lane << 2));
#pragma unroll
    for (int u = 0; u < D; ++u) {
        uint4 W = recs[o + j + u];
        unsigned sel = (h4 & 2) ? W.y : W.x;
        float a = hodd ? bfhi(sel) : bflo(sel);
        aeS += (float)((int)(W.w << sh1) >> 24);
        dn += a;
        f32x2 lo2 = __builtin_amdgcn_cvt_pk_f32_fp8((int)rv[u], false);
        f32x2 hi2 = __builtin_amdgcn_cvt_pk_f32_fp8((int)rv[u], true);
        acc0 += a * lo2.x; acc1 += a * lo2.y;
        acc2 += a * hi2.x; acc3 += a * hi2.y;
    }
}

// process one node's record sub-range (batch-8 ladder)
__device__ __forceinline__ void node_range(
    const uint4* recs, int o, int c, const unsigned char* xwf8, int lane,
    int h4, bool hodd, int sh1,
    float& acc0, float& acc1, float& acc2, float& acc3, float& dn, float& aeS) {
    int j = 0;
    for (; j + 8 <= c; j += 8)
        gather_batch<8>(recs, o, j, xwf8, lane, h4, hodd, sh1, acc0, acc1, acc2, acc3, dn, aeS);
    if (j + 4 <= c) {
        gather_batch<4>(recs, o, j, xwf8, lane, h4, hodd, sh1, acc0, acc1, acc2, acc3, dn, aeS);
        j += 4;
    }
    for (; j < c; ++j)
        gather_batch<1>(recs, o, j, xwf8, lane, h4, hodd, sh1, acc0, acc1, acc2, acc3, dn, aeS);
}

// ------- fused gather + softmax + aggregate + MFMA proj + LN -------
// 512 threads: 16 nodes/block, 8 waves, each wave owns 2 contiguous nodes.
// LDS union: recs (gather phase) overlaps gbf+pC (projection phase).
#define LDS_BYTES (NPB * 272 * 2 + NPB * 66 * 4)   // 8704 + 4224 = 12928
__global__ void __launch_bounds__(512)
k_gather_out(const int* __restrict__ row_start, const int* __restrict__ cnt,
             const uint4* __restrict__ recp,
             const float* __restrict__ a_src, const float* __restrict__ a_dst,
             const unsigned char* __restrict__ xwf8, const float* __restrict__ x,
             const float* __restrict__ bias, const unsigned short* __restrict__ WpT,
             const float* __restrict__ bp, const float* __restrict__ gamma,
             const float* __restrict__ beta, float* __restrict__ out, int n) {
    int tid = threadIdx.x, lane = tid & 63, wv = tid >> 6;   // wv in 0..7
    int h4 = lane >> 4;
    bool hodd = (h4 & 1);
    int sh1 = (3 - h4) * 8;

    __shared__ __align__(16) unsigned char ldsbuf[LDS_BYTES];
    uint4* recs = (uint4*)ldsbuf;                                        // [CAP] (8 KB)
    unsigned short (*gbf)[272] = (unsigned short (*)[272])ldsbuf;        // [NPB][272]
    float (*pC)[66] = (float (*)[66])(ldsbuf + NPB * 272 * 2);           // [NPB][66]

    int first = blockIdx.x * NPB;
    int last = min(first + NPB, n) - 1;
    int rs0 = row_start[first];
    int total = row_start[last] + cnt[last] - rs0;

    // this wave's 2 contiguous nodes
    int nd[2], dgq[2], mLo[2], mHi[2];
#pragma unroll
    for (int q = 0; q < 2; ++q) {
        int node = first + wv * 2 + q;
        bool v = node < n;
        int nc = v ? node : n - 1;
        nd[q] = nc;
        dgq[q] = v ? cnt[nc] : 0;
        mLo[q] = row_start[nc] - rs0;
        mHi[q] = mLo[q] + dgq[q];
    }

    float a00 = 0.f, a01 = 0.f, a02 = 0.f, a03 = 0.f, dn0 = 0.f, ae0 = 0.f;
    float a10 = 0.f, a11 = 0.f, a12 = 0.f, a13 = 0.f, dn1 = 0.f, ae1 = 0.f;

    for (int base = 0; base < total; base += CAP) {
        int cend = min(total, base + CAP);
        if (base) __syncthreads();
        for (int idx = base + tid; idx < cend; idx += 512)
            recs[idx - base] = recp[rs0 + idx];
        __syncthreads();
        {
            int lo = max(mLo[0], base), hi = min(mHi[0], cend);
            if (hi > lo) node_range(recs, lo - base, hi - lo, xwf8, lane, h4, hodd, sh1,
                                    a00, a01, a02, a03, dn0, ae0);
        }
        {
            int lo = max(mLo[1], base), hi = min(mHi[1], cend);
            if (hi > lo) node_range(recs, lo - base, hi - lo, xwf8, lane, h4, hodd, sh1,
                                    a10, a11, a12, a13, dn1, ae1);
        }
    }
    __syncthreads();   // recs lifetime ends; gbf/pC aliases become live

    // finalize each of the wave's 2 nodes: self-loop + normalize + bias -> bf16 g
    float4 bv = *(const float4*)(bias + (lane << 2));
#pragma unroll
    for (int q = 0; q < 2; ++q) {
        float A0 = (q == 0) ? a00 : a10;
        float A1 = (q == 0) ? a01 : a11;
        float A2 = (q == 0) ? a02 : a12;
        float A3 = (q == 0) ? a03 : a13;
        float DN = (q == 0) ? dn0 : dn1;
        float AE = (q == 0) ? ae0 : ae1;
        int nc = nd[q];
        float as = a_src[nc * HEADS + h4];
        float ad = a_dst[nc * HEADS + h4];
        unsigned int sr8 = *(const unsigned int*)(xwf8 + (size_t)nc * HC + (lane << 2));
        float cf = fmaxf((float)dgq[q], 1.0f);
        float al = as + ad + (AE * (1.0f / 32.0f)) / cf;
        al = al >= 0.f ? al : NEG_SLOPE * al;
        float el = __expf(al);
        float inv = 1.0f / (DN + el);
        f32x2 slo = __builtin_amdgcn_cvt_pk_f32_fp8((int)sr8, false);
        f32x2 shi = __builtin_amdgcn_cvt_pk_f32_fp8((int)sr8, true);
        ushort4 gv;
        gv.x = bfb((A0 + el * slo.x) * inv + bv.x);
        gv.y = bfb((A1 + el * slo.y) * inv + bv.y);
        gv.z = bfb((A2 + el * shi.x) * inv + bv.z);
        gv.w = bfb((A3 + el * shi.y) * inv + bv.w);
        *(ushort4*)&gbf[wv * 2 + q][lane << 2] = gv;
    }
    __syncthreads();

    // MFMA projection: full M=16. waves 0-3: wave wv computes col tile wv of
    // g(16x256) @ Wp(256x64). waves 4-7 idle (cheap).
    if (wv < 4) {
        int g = lane >> 4, r16 = lane & 15;
        const unsigned short* wp = WpT + (size_t)(wv * 16 + r16) * HC + 8 * g;
        const unsigned short* ga = &gbf[r16][8 * g];
        f32x4 pacc = {0.f, 0.f, 0.f, 0.f};
#pragma unroll
        for (int kk = 0; kk < 8; ++kk) {
            short8 Af = *(const short8*)(ga + kk * 32);
            short8 Bf = *(const short8*)(wp + kk * 32);
            pacc = __builtin_amdgcn_mfma_f32_16x16x32_bf16(Af, Bf, pacc, 0, 0, 0);
        }
#pragma unroll
        for (int m = 0; m < 4; ++m) pC[4 * g + m][wv * 16 + r16] = pacc[m];
    }
    __syncthreads();

    // epilogue: 2 passes; pass p -> local node wv + 8p; lane = channel
#pragma unroll
    for (int p = 0; p < 2; ++p) {
        int local = wv + 8 * p;
        int node = first + local;
        bool v2 = node < n;
        float pv = pC[local][lane] + bp[lane];
        float elv = pv > 0.f ? pv : expm1f(pv);
        float xv = v2 ? x[(size_t)node * EMB + lane] : 0.f;
        float hv = xv + elv;
        float s1 = hv, s2 = hv * hv;
        for (int off = 32; off > 0; off >>= 1) {
            s1 += __shfl_xor(s1, off);
            s2 += __shfl_xor(s2, off);
        }
        float mu = s1 * (1.0f / EMB);
        float var = s2 * (1.0f / EMB) - mu * mu;
        if (v2)
            out[(size_t)node * EMB + lane] =
                (hv - mu) * rsqrtf(var + LN_EPS) * gamma[lane] + beta[lane];
    }
}

extern "C" void kernel_launch(void* const* d_in, const int* in_sizes, int n_in,
                              void* d_out, int out_size, void* d_ws, size_t ws_size,
                              hipStream_t stream) {
    const float* x        = (const float*)d_in[0];
    const int*   ei       = (const int*)d_in[1];
    const float* edge_attr= (const float*)d_in[2];
    const float* W        = (const float*)d_in[3];
    const float* W_edge   = (const float*)d_in[4];
    const float* att_src  = (const float*)d_in[5];
    const float* att_dst  = (const float*)d_in[6];
    const float* att_edge = (const float*)d_in[7];
    const float* bias     = (const float*)d_in[8];
    const float* Wp       = (const float*)d_in[9];
    const float* bp       = (const float*)d_in[10];
    const float* gamma    = (const float*)d_in[11];
    const float* beta     = (const float*)d_in[12];
    float* out = (float*)d_out;

    int n = in_sizes[0] / EMB;
    int E = in_sizes[1] / 2;
    int nb = (n + 255) / 256;

    float* ws = (float*)d_ws;
    float* a_src       = ws; ws += (size_t)n * HEADS;
    float* a_dst       = ws; ws += (size_t)n * HEADS;
    float* we_att      = ws; ws += EDGE_DIM * HEADS;
    unsigned char* xwf8 = (unsigned char*)ws; ws += (size_t)n * HC / 4;   // 1B/elem
    uint4* recp        = (uint4*)ws; ws += (size_t)E * 4;    // 16B/edge
    uint2* aeb         = (uint2*)ws; ws += (size_t)E * 2;    // 8B/edge
    unsigned short* WpT = (unsigned short*)ws; ws += HC * EMB / 2;
    unsigned short* WxT = (unsigned short*)ws; ws += NCOLS * EMB / 2;
    int* iw = (int*)ws;
    int* cnt       = iw; iw += n;
    int* rank      = iw; iw += E;
    int* row_start = iw; iw += n;
    int* tmp       = iw; iw += n;
    int* bsum      = iw; iw += 256;

    const int tb = 256;
    hipLaunchKernelGGL(k_prep, dim3((n + tb - 1) / tb), dim3(tb), 0, stream,
                       W_edge, att_edge, we_att, Wp, WpT, W, att_src, att_dst, WxT, cnt, n);
    hipLaunchKernelGGL(k_xw_mfma, dim3((n + 15) / 16), dim3(tb), 0, stream,
                       x, WxT, xwf8, a_src, a_dst, n, ei, edge_attr, we_att, cnt, rank, aeb, E);
    hipLaunchKernelGGL(k_scan1, dim3(nb), dim3(tb), 0, stream, cnt, tmp, bsum, n);
    hipLaunchKernelGGL(k_scan2, dim3(1), dim3(tb), 0, stream, bsum, nb);
    hipLaunchKernelGGL(k_scan3, dim3(nb), dim3(tb), 0, stream, tmp, cnt, bsum, row_start, n);
    hipLaunchKernelGGL(k_scatter, dim3((E + tb - 1) / tb), dim3(tb), 0, stream,
                       ei, aeb, a_src, a_dst, row_start, rank, recp, E);
    hipLaunchKernelGGL(k_gather_out, dim3((n + NPB - 1) / NPB), dim3(512), 0, stream,
                       row_start, cnt, recp, a_src, a_dst, xwf8, x, bias, WpT, bp,
                       gamma, beta, out, n);
}

// Round 19
// 146.720 us; speedup vs baseline: 1.0398x; 1.0398x over previous
//
#include <hip/hip_runtime.h>
#include <hip/hip_bf16.h>
#include <hip/hip_fp8.h>
#include <math.h>

#define EMB 64
#define HEADS 4
#define HC 256
#define EDGE_DIM 16
#define NEG_SLOPE 0.2f
#define LN_EPS 1e-5f
#define NCOLS 272   // 256 xw cols + 4 a_src + 4 a_dst + 8 pad
#define CAP 512     // records staged in LDS per chunk
#define NPB 16      // nodes per block (4 per wave)

typedef __attribute__((ext_vector_type(8))) short short8;
typedef __attribute__((ext_vector_type(4))) float f32x4;
typedef __attribute__((ext_vector_type(2))) float f32x2;

__device__ __forceinline__ float bflo(unsigned int u) { return __uint_as_float(u << 16); }
__device__ __forceinline__ float bfhi(unsigned int u) { return __uint_as_float(u & 0xffff0000u); }
__device__ __forceinline__ unsigned short bfb(float f) {
    __hip_bfloat16 h = __float2bfloat16(f);
    return *(unsigned short*)&h;
}
__device__ __forceinline__ unsigned int pack_bf2(float a, float b) {
    return (unsigned int)bfb(a) | ((unsigned int)bfb(b) << 16);
}
__device__ __forceinline__ unsigned char ftofp8(float f) {
    __hip_fp8_e4m3 t(f); return (unsigned char)t.__x;
}

#if __has_builtin(__builtin_amdgcn_sdot4)
#define AE_DOT 1
#else
#define AE_DOT 0
#endif

// prep: zero cnt; we_att; WpT[64][256] bf16 (transposed Wp); WxT[272][64] bf16
__global__ void k_prep(const float* __restrict__ W_edge, const float* __restrict__ att_edge,
                       float* __restrict__ we_att, const float* __restrict__ Wp,
                       unsigned short* __restrict__ WpT, const float* __restrict__ W,
                       const float* __restrict__ att_src, const float* __restrict__ att_dst,
                       unsigned short* __restrict__ WxT, int* __restrict__ cnt, int n) {
    int i = blockIdx.x * blockDim.x + threadIdx.x;
    if (i < n) cnt[i] = 0;
    if (i < EDGE_DIM * HEADS) {
        int d = i >> 2, h = i & 3;
        float acc = 0.0f;
#pragma unroll
        for (int c = 0; c < EMB; ++c)
            acc += W_edge[d * HC + h * EMB + c] * att_edge[h * EMB + c];
        we_att[d * HEADS + h] = acc;
    }
    if (i < HC * EMB) {
        int k = i >> 8, jj = i & 255;              // WpT[k][jj] = Wp[jj][k]
        WpT[i] = bfb(Wp[jj * EMB + k]);
    }
    if (i < NCOLS * EMB) {
        int c = i >> 6, k = i & 63;
        float v = 0.0f;
        if (c < HC) {
            v = W[k * HC + c];
        } else if (c < HC + 4) {
            int h = c - HC;
            float s = 0.0f;
#pragma unroll
            for (int j = 0; j < EMB; ++j) s += W[k * HC + h * EMB + j] * att_src[h * EMB + j];
            v = s;
        } else if (c < HC + 8) {
            int h = c - HC - 4;
            float s = 0.0f;
#pragma unroll
            for (int j = 0; j < EMB; ++j) s += W[k * HC + h * EMB + j] * att_dst[h * EMB + j];
            v = s;
        }
        WxT[i] = bfb(v);
    }
}

// ---- MFMA GEMM: [xw(fp8) | a_src | a_dst] = x @ Wx ; 16 nodes/block, 4 waves ----
// fused tail: rank atomic + edge-attn projection ae = edge_attr . we_att (bf16x4)
__global__ void __launch_bounds__(256)
k_xw_mfma(const float* __restrict__ x, const unsigned short* __restrict__ WxT,
          unsigned char* __restrict__ xwf8, float* __restrict__ a_src,
          float* __restrict__ a_dst, int n,
          const int* __restrict__ ei, const float* __restrict__ edge_attr,
          const float* __restrict__ we_att, int* __restrict__ cnt,
          int* __restrict__ rank, uint2* __restrict__ aeb, int E) {
    int tid = threadIdx.x, lane = tid & 63, wv = tid >> 6;
    int g = lane >> 4, r16 = lane & 15;
    __shared__ float wa[EDGE_DIM * HEADS];
    if (tid < EDGE_DIM * HEADS) wa[tid] = we_att[tid];
    __syncthreads();

    int mbase = blockIdx.x * 16;
    int row = mbase + r16;
    if (row >= n) row = n - 1;

    const float* xr = x + (size_t)row * EMB;
    short8 A[2];
#pragma unroll
    for (int kk = 0; kk < 2; ++kk) {
        float4 f0 = *(const float4*)(xr + kk * 32 + 8 * g);
        float4 f1 = *(const float4*)(xr + kk * 32 + 8 * g + 4);
        short8 a;
        a[0] = (short)bfb(f0.x); a[1] = (short)bfb(f0.y);
        a[2] = (short)bfb(f0.z); a[3] = (short)bfb(f0.w);
        a[4] = (short)bfb(f1.x); a[5] = (short)bfb(f1.y);
        a[6] = (short)bfb(f1.z); a[7] = (short)bfb(f1.w);
        A[kk] = a;
    }

    for (int t = wv; t <= 16; t += 4) {
        int col = t * 16 + r16;
        const unsigned short* bp = WxT + (size_t)col * EMB + 8 * g;
        short8 B0 = *(const short8*)(bp);
        short8 B1 = *(const short8*)(bp + 32);
        f32x4 acc = {0.f, 0.f, 0.f, 0.f};
        acc = __builtin_amdgcn_mfma_f32_16x16x32_bf16(A[0], B0, acc, 0, 0, 0);
        acc = __builtin_amdgcn_mfma_f32_16x16x32_bf16(A[1], B1, acc, 0, 0, 0);
        if (t < 16) {
#pragma unroll
            for (int r = 0; r < 4; ++r) {
                int node = mbase + 4 * g + r;
                if (node < n) xwf8[(size_t)node * HC + col] = ftofp8(acc[r]);
            }
        } else {
#pragma unroll
            for (int r = 0; r < 4; ++r) {
                int node = mbase + 4 * g + r;
                if (node < n) {
                    if (r16 < 4) a_src[node * HEADS + r16] = acc[r];
                    else if (r16 < 8) a_dst[node * HEADS + r16 - 4] = acc[r];
                }
            }
        }
    }

    // fused tail: rank atomic + ae projection (hides edge_attr stream under atomics)
    int stride = gridDim.x * blockDim.x;
    for (int e = blockIdx.x * blockDim.x + tid; e < E; e += stride) {
        rank[e] = atomicAdd(&cnt[ei[E + e]], 1);
        const float4* ea4 = (const float4*)(edge_attr + (size_t)e * EDGE_DIM);
        float ae[HEADS] = {0.f, 0.f, 0.f, 0.f};
#pragma unroll
        for (int q = 0; q < 4; ++q) {
            float4 v4 = ea4[q];
            const float* vp = (const float*)&v4;
#pragma unroll
            for (int r = 0; r < 4; ++r) {
                float v = vp[r];
                int dd = q * 4 + r;
#pragma unroll
                for (int h = 0; h < HEADS; ++h) ae[h] += v * wa[dd * HEADS + h];
            }
        }
        uint2 ab;
        ab.x = pack_bf2(ae[0], ae[1]);
        ab.y = pack_bf2(ae[2], ae[3]);
        aeb[e] = ab;
    }
}

// ---------------- 3-dispatch exclusive scan over cnt[n] ----------------
__global__ void k_scan1(const int* __restrict__ cnt, int* __restrict__ tmp,
                        int* __restrict__ bsum, int n) {
    __shared__ int s[256];
    int i = blockIdx.x * 256 + threadIdx.x;
    int v = (i < n) ? cnt[i] : 0;
    s[threadIdx.x] = v;
    __syncthreads();
    for (int off = 1; off < 256; off <<= 1) {
        int t = (threadIdx.x >= off) ? s[threadIdx.x - off] : 0;
        __syncthreads();
        s[threadIdx.x] += t;
        __syncthreads();
    }
    if (i < n) tmp[i] = s[threadIdx.x];
    if (threadIdx.x == 255) bsum[blockIdx.x] = s[255];
}

__global__ void k_scan2(int* __restrict__ bsum, int nb) {
    __shared__ int s[256];
    int v = (threadIdx.x < nb) ? bsum[threadIdx.x] : 0;
    s[threadIdx.x] = v;
    __syncthreads();
    for (int off = 1; off < 256; off <<= 1) {
        int t = (threadIdx.x >= off) ? s[threadIdx.x - off] : 0;
        __syncthreads();
        s[threadIdx.x] += t;
        __syncthreads();
    }
    if (threadIdx.x < nb) bsum[threadIdx.x] = s[threadIdx.x] - v; // exclusive
}

__global__ void k_scan3(const int* __restrict__ tmp, const int* __restrict__ cnt,
                        const int* __restrict__ bsum, int* __restrict__ row_start, int n) {
    int i = blockIdx.x * 256 + threadIdx.x;
    if (i < n) row_start[i] = tmp[i] - cnt[i] + bsum[blockIdx.x];
}

// ---- scatter: alpha from precomputed ae (8B/edge); 16B CSR record write ----
// record = { ea01.bf16x2, ea23.bf16x2, src.u32, ae.int8x4 (scale 1/32) }
__global__ void k_scatter(const int* __restrict__ ei, const uint2* __restrict__ aeb,
                          const float* __restrict__ a_src, const float* __restrict__ a_dst,
                          const int* __restrict__ row_start, const int* __restrict__ rank,
                          uint4* __restrict__ recp, int E) {
    int e = blockIdx.x * blockDim.x + threadIdx.x;
    if (e >= E) return;
    int s = ei[e], d = ei[E + e];
    uint2 ab = aeb[e];
    float ae[HEADS];
    ae[0] = bflo(ab.x); ae[1] = bfhi(ab.x);
    ae[2] = bflo(ab.y); ae[3] = bfhi(ab.y);
    float4 as4 = *(const float4*)(a_src + (size_t)s * HEADS);
    float4 ad4 = *(const float4*)(a_dst + (size_t)d * HEADS);
    const float* asp = (const float*)&as4;
    const float* adp = (const float*)&ad4;
    float ea[HEADS];
    unsigned int aeq = 0;
#pragma unroll
    for (int h = 0; h < HEADS; ++h) {
        float al = asp[h] + adp[h] + ae[h];
        al = al >= 0.0f ? al : NEG_SLOPE * al;
        ea[h] = __expf(al);          // no max-subtraction needed: |al| < ~8
        int q = __float2int_rn(ae[h] * 32.0f);
        q = max(-127, min(127, q));
        aeq |= ((unsigned int)(q & 0xff)) << (8 * h);
    }
    int pos = row_start[d] + rank[e];
    uint4 w;
    w.x = pack_bf2(ea[0], ea[1]);
    w.y = pack_bf2(ea[2], ea[3]);
    w.z = (unsigned int)s;
    w.w = aeq;
    recp[pos] = w;
}

// two-phase gather batch: issue D independent row loads, then decode+accumulate.
// ae accumulated as packed-int via v_dot4_i32_i8 (1 inst vs 4).
template<int D>
__device__ __forceinline__ void gather_batch(
    const uint4* recs, int o, int j, const unsigned char* xwf8, int lane,
    int h4, bool hodd, int aemask,
    float& acc0, float& acc1, float& acc2, float& acc3, float& dn, int& aeI) {
    int sv[D];
#pragma unroll
    for (int u = 0; u < D; ++u) sv[u] = (int)recs[o + j + u].z;
    unsigned int rv[D];
#pragma unroll
    for (int u = 0; u < D; ++u)
        rv[u] = *(const unsigned int*)(xwf8 + (size_t)sv[u] * HC + (lane << 2));
#pragma unroll
    for (int u = 0; u < D; ++u) {
        uint4 W = recs[o + j + u];
        unsigned sel = (h4 & 2) ? W.y : W.x;
        float a = hodd ? bfhi(sel) : bflo(sel);
#if AE_DOT
        aeI = __builtin_amdgcn_sdot4((int)W.w, aemask, aeI, false);
#else
        aeI += (int)((int)(W.w << ((3 - h4) * 8)) >> 24);
#endif
        dn += a;
        f32x2 lo2 = __builtin_amdgcn_cvt_pk_f32_fp8((int)rv[u], false);
        f32x2 hi2 = __builtin_amdgcn_cvt_pk_f32_fp8((int)rv[u], true);
        acc0 += a * lo2.x; acc1 += a * lo2.y;
        acc2 += a * hi2.x; acc3 += a * hi2.y;
    }
}

// process one node's record sub-range (batch-8 ladder)
__device__ __forceinline__ void node_range(
    const uint4* recs, int o, int c, const unsigned char* xwf8, int lane,
    int h4, bool hodd, int aemask,
    float& acc0, float& acc1, float& acc2, float& acc3, float& dn, int& aeI) {
    int j = 0;
    for (; j + 8 <= c; j += 8)
        gather_batch<8>(recs, o, j, xwf8, lane, h4, hodd, aemask, acc0, acc1, acc2, acc3, dn, aeI);
    if (j + 4 <= c) {
        gather_batch<4>(recs, o, j, xwf8, lane, h4, hodd, aemask, acc0, acc1, acc2, acc3, dn, aeI);
        j += 4;
    }
    for (; j < c; ++j)
        gather_batch<1>(recs, o, j, xwf8, lane, h4, hodd, aemask, acc0, acc1, acc2, acc3, dn, aeI);
}

// ------- fused gather + softmax + aggregate + MFMA proj + LN -------
// 256 threads: 16 nodes/block, each wave owns 4 contiguous nodes.
// LDS union: recs (gather phase) overlaps gbf+pC (projection phase).
#define LDS_BYTES (NPB * 272 * 2 + NPB * 66 * 4)   // 8704 + 4224 = 12928
__global__ void __launch_bounds__(256)
k_gather_out(const int* __restrict__ row_start, const int* __restrict__ cnt,
             const uint4* __restrict__ recp,
             const float* __restrict__ a_src, const float* __restrict__ a_dst,
             const unsigned char* __restrict__ xwf8, const float* __restrict__ x,
             const float* __restrict__ bias, const unsigned short* __restrict__ WpT,
             const float* __restrict__ bp, const float* __restrict__ gamma,
             const float* __restrict__ beta, float* __restrict__ out, int n) {
    int tid = threadIdx.x, lane = tid & 63, wv = tid >> 6;
    int h4 = lane >> 4;
    bool hodd = (h4 & 1);
    int aemask = 1 << (8 * h4);     // byte-select mask for sdot4

    __shared__ __align__(16) unsigned char ldsbuf[LDS_BYTES];
    uint4* recs = (uint4*)ldsbuf;                                        // [CAP] (8 KB)
    unsigned short (*gbf)[272] = (unsigned short (*)[272])ldsbuf;        // [NPB][272]
    float (*pC)[66] = (float (*)[66])(ldsbuf + NPB * 272 * 2);           // [NPB][66]

    int first = blockIdx.x * NPB;
    int last = min(first + NPB, n) - 1;
    int rs0 = row_start[first];
    int total = row_start[last] + cnt[last] - rs0;

    // this wave's 4 nodes (contiguous)
    int nd[4], dgq[4], mLo[4], mHi[4];
#pragma unroll
    for (int q = 0; q < 4; ++q) {
        int node = first + wv * 4 + q;
        bool v = node < n;
        int nc = v ? node : n - 1;
        nd[q] = nc;
        dgq[q] = v ? cnt[nc] : 0;
        mLo[q] = row_start[nc] - rs0;
        mHi[q] = mLo[q] + dgq[q];
    }

    float a00 = 0.f, a01 = 0.f, a02 = 0.f, a03 = 0.f, dn0 = 0.f;
    float a10 = 0.f, a11 = 0.f, a12 = 0.f, a13 = 0.f, dn1 = 0.f;
    float a20 = 0.f, a21 = 0.f, a22 = 0.f, a23 = 0.f, dn2 = 0.f;
    float a30 = 0.f, a31 = 0.f, a32 = 0.f, a33 = 0.f, dn3 = 0.f;
    int ae0 = 0, ae1 = 0, ae2 = 0, ae3 = 0;

    for (int base = 0; base < total; base += CAP) {
        int cend = min(total, base + CAP);
        if (base) __syncthreads();
        for (int idx = base + tid; idx < cend; idx += 256)
            recs[idx - base] = recp[rs0 + idx];
        __syncthreads();
        {
            int lo = max(mLo[0], base), hi = min(mHi[0], cend);
            if (hi > lo) node_range(recs, lo - base, hi - lo, xwf8, lane, h4, hodd, aemask,
                                    a00, a01, a02, a03, dn0, ae0);
        }
        {
            int lo = max(mLo[1], base), hi = min(mHi[1], cend);
            if (hi > lo) node_range(recs, lo - base, hi - lo, xwf8, lane, h4, hodd, aemask,
                                    a10, a11, a12, a13, dn1, ae1);
        }
        {
            int lo = max(mLo[2], base), hi = min(mHi[2], cend);
            if (hi > lo) node_range(recs, lo - base, hi - lo, xwf8, lane, h4, hodd, aemask,
                                    a20, a21, a22, a23, dn2, ae2);
        }
        {
            int lo = max(mLo[3], base), hi = min(mHi[3], cend);
            if (hi > lo) node_range(recs, lo - base, hi - lo, xwf8, lane, h4, hodd, aemask,
                                    a30, a31, a32, a33, dn3, ae3);
        }
    }
    __syncthreads();   // recs lifetime ends; gbf/pC aliases become live

    // finalize each of the wave's 4 nodes: self-loop + normalize + bias -> bf16 g
    float4 bv = *(const float4*)(bias + (lane << 2));
#pragma unroll
    for (int q = 0; q < 4; ++q) {
        float A0 = (q == 0) ? a00 : (q == 1) ? a10 : (q == 2) ? a20 : a30;
        float A1 = (q == 0) ? a01 : (q == 1) ? a11 : (q == 2) ? a21 : a31;
        float A2 = (q == 0) ? a02 : (q == 1) ? a12 : (q == 2) ? a22 : a32;
        float A3 = (q == 0) ? a03 : (q == 1) ? a13 : (q == 2) ? a23 : a33;
        float DN = (q == 0) ? dn0 : (q == 1) ? dn1 : (q == 2) ? dn2 : dn3;
        float AE = (float)((q == 0) ? ae0 : (q == 1) ? ae1 : (q == 2) ? ae2 : ae3);
        int nc = nd[q];
        float as = a_src[nc * HEADS + h4];
        float ad = a_dst[nc * HEADS + h4];
        unsigned int sr8 = *(const unsigned int*)(xwf8 + (size_t)nc * HC + (lane << 2));
        float cf = fmaxf((float)dgq[q], 1.0f);
        float al = as + ad + (AE * (1.0f / 32.0f)) / cf;
        al = al >= 0.f ? al : NEG_SLOPE * al;
        float el = __expf(al);
        float inv = 1.0f / (DN + el);
        f32x2 slo = __builtin_amdgcn_cvt_pk_f32_fp8((int)sr8, false);
        f32x2 shi = __builtin_amdgcn_cvt_pk_f32_fp8((int)sr8, true);
        ushort4 gv;
        gv.x = bfb((A0 + el * slo.x) * inv + bv.x);
        gv.y = bfb((A1 + el * slo.y) * inv + bv.y);
        gv.z = bfb((A2 + el * shi.x) * inv + bv.z);
        gv.w = bfb((A3 + el * shi.y) * inv + bv.w);
        *(ushort4*)&gbf[wv * 4 + q][lane << 2] = gv;
    }
    __syncthreads();

    // MFMA projection: full M=16. wave wv computes col tile wv of g(16x256) @ Wp(256x64)
    {
        int g = lane >> 4, r16 = lane & 15;
        const unsigned short* wp = WpT + (size_t)(wv * 16 + r16) * HC + 8 * g;
        const unsigned short* ga = &gbf[r16][8 * g];
        f32x4 pacc = {0.f, 0.f, 0.f, 0.f};
#pragma unroll
        for (int kk = 0; kk < 8; ++kk) {
            short8 Af = *(const short8*)(ga + kk * 32);
            short8 Bf = *(const short8*)(wp + kk * 32);
            pacc = __builtin_amdgcn_mfma_f32_16x16x32_bf16(Af, Bf, pacc, 0, 0, 0);
        }
#pragma unroll
        for (int m = 0; m < 4; ++m) pC[4 * g + m][wv * 16 + r16] = pacc[m];
    }
    __syncthreads();

    // epilogue: 4 passes; pass p -> local node wv + 4p; lane = channel
#pragma unroll
    for (int p = 0; p < 4; ++p) {
        int local = wv + 4 * p;
        int node = first + local;
        bool v2 = node < n;
        float pv = pC[local][lane] + bp[lane];
        float elv = pv > 0.f ? pv : expm1f(pv);
        float xv = v2 ? x[(size_t)node * EMB + lane] : 0.f;
        float hv = xv + elv;
        float s1 = hv, s2 = hv * hv;
        for (int off = 32; off > 0; off >>= 1) {
            s1 += __shfl_xor(s1, off);
            s2 += __shfl_xor(s2, off);
        }
        float mu = s1 * (1.0f / EMB);
        float var = s2 * (1.0f / EMB) - mu * mu;
        if (v2)
            out[(size_t)node * EMB + lane] =
                (hv - mu) * rsqrtf(var + LN_EPS) * gamma[lane] + beta[lane];
    }
}

extern "C" void kernel_launch(void* const* d_in, const int* in_sizes, int n_in,
                              void* d_out, int out_size, void* d_ws, size_t ws_size,
                              hipStream_t stream) {
    const float* x        = (const float*)d_in[0];
    const int*   ei       = (const int*)d_in[1];
    const float* edge_attr= (const float*)d_in[2];
    const float* W        = (const float*)d_in[3];
    const float* W_edge   = (const float*)d_in[4];
    const float* att_src  = (const float*)d_in[5];
    const float* att_dst  = (const float*)d_in[6];
    const float* att_edge = (const float*)d_in[7];
    const float* bias     = (const float*)d_in[8];
    const float* Wp       = (const float*)d_in[9];
    const float* bp       = (const float*)d_in[10];
    const float* gamma    = (const float*)d_in[11];
    const float* beta     = (const float*)d_in[12];
    float* out = (float*)d_out;

    int n = in_sizes[0] / EMB;
    int E = in_sizes[1] / 2;
    int nb = (n + 255) / 256;

    float* ws = (float*)d_ws;
    float* a_src       = ws; ws += (size_t)n * HEADS;
    float* a_dst       = ws; ws += (size_t)n * HEADS;
    float* we_att      = ws; ws += EDGE_DIM * HEADS;
    unsigned char* xwf8 = (unsigned char*)ws; ws += (size_t)n * HC / 4;   // 1B/elem
    uint4* recp        = (uint4*)ws; ws += (size_t)E * 4;    // 16B/edge
    uint2* aeb         = (uint2*)ws; ws += (size_t)E * 2;    // 8B/edge
    unsigned short* WpT = (unsigned short*)ws; ws += HC * EMB / 2;
    unsigned short* WxT = (unsigned short*)ws; ws += NCOLS * EMB / 2;
    int* iw = (int*)ws;
    int* cnt       = iw; iw += n;
    int* rank      = iw; iw += E;
    int* row_start = iw; iw += n;
    int* tmp       = iw; iw += n;
    int* bsum      = iw; iw += 256;

    const int tb = 256;
    hipLaunchKernelGGL(k_prep, dim3((n + tb - 1) / tb), dim3(tb), 0, stream,
                       W_edge, att_edge, we_att, Wp, WpT, W, att_src, att_dst, WxT, cnt, n);
    hipLaunchKernelGGL(k_xw_mfma, dim3((n + 15) / 16), dim3(tb), 0, stream,
                       x, WxT, xwf8, a_src, a_dst, n, ei, edge_attr, we_att, cnt, rank, aeb, E);
    hipLaunchKernelGGL(k_scan1, dim3(nb), dim3(tb), 0, stream, cnt, tmp, bsum, n);
    hipLaunchKernelGGL(k_scan2, dim3(1), dim3(tb), 0, stream, bsum, nb);
    hipLaunchKernelGGL(k_scan3, dim3(nb), dim3(tb), 0, stream, tmp, cnt, bsum, row_start, n);
    hipLaunchKernelGGL(k_scatter, dim3((E + tb - 1) / tb), dim3(tb), 0, stream,
                       ei, aeb, a_src, a_dst, row_start, rank, recp, E);
    hipLaunchKernelGGL(k_gather_out, dim3((n + NPB - 1) / NPB), dim3(tb), 0, stream,
                       row_start, cnt, recp, a_src, a_dst, xwf8, x, bias, WpT, bp,
                       gamma, beta, out, n);
}